// Round 7
// baseline (95.172 us; speedup 1.0000x reference)
//
#include <hip/hip_runtime.h>

// Channel_mixing8: per-pixel (B*H*W = 32768) over C=64 channels:
//   attn[i,j] = softmax_i( v[i]*k[j] );  out[i] = sum_j attn[i,j] * q[j]
// Restructured: S_j = sum_i exp(v_i k_j);  out_i = sum_j (q_j / S_j) * exp(v_i k_j)
//
// R7: R3-R6 evidence -> trans pipe (v_exp_f32) is the floor (~16cy/wave64) and
// VALU-issue cuts only nibble. Fix: 50/50 hybrid exp. Half the elements use
// v_exp_f32 (trans pipe); half use a full-rate-VALU bit-trick exp2:
//   t = (x+127)*2^23; i = (int)t  (t>0 so trunc==floor)
//   e_lin = bitcast<float>(i) = 2^n * (1+f),  f = fract(x)   [exact]
//   e = e_lin * g(f),  g(f) = 2^f/(1+f), cubic interp at {0,1/3,2/3,1},
//   max rel err ~1.3e-3 -> output err ~0.01 << 0.16 threshold.
// Both pipes run concurrently from the same/different waves.

constexpr int C    = 64;
constexpr int HW   = 128 * 128;          // 16384 = 1<<14
constexpr int NPIX = 2 * HW;             // 32768
constexpr int JT   = 4;                  // j-tile
constexpr int PXB  = 32;                 // pixels per block
constexpr int LSTR = 68;                 // LDS row stride (floats); 272B, 16B-aligned
#define LOG2E 1.4426950408889634f
// g(f) = 1 + GB*f + GC*f^2 + GD*f^3
#define GB (-0.281515f)
#define GC ( 0.382763f)
#define GD (-0.101248f)
#define MAGS 8388608.0f        // 2^23
#define MAGB 1065353216.0f     // 127 * 2^23

template <int CTRL>
__device__ __forceinline__ float dpp_add(float x) {
  int xi = __builtin_bit_cast(int, x);
  int yi = __builtin_amdgcn_update_dpp(0, xi, CTRL, 0xF, 0xF, true);
  return x + __builtin_bit_cast(float, yi);
}

// full-rate-VALU exp2 (no trans pipe): valid for |x| < ~100, f32 inputs
__device__ __forceinline__ float exp2_valu(float x) {
  float t = fmaf(x, MAGS, MAGB);
  int   i = (int)t;                              // v_cvt_i32_f32 (full rate)
  float f = __builtin_amdgcn_fractf(x);          // v_fract_f32  (full rate)
  float g = fmaf(fmaf(fmaf(GD, f, GC), f, GB), f, 1.0f);
  return __builtin_bit_cast(float, i) * g;
}

__global__ __launch_bounds__(256, 4) void channel_mixing_kernel(
    const float* __restrict__ q,    // x
    const float* __restrict__ kk,   // y
    const float* __restrict__ v,    // z
    float* __restrict__ out) {
  __shared__ __align__(16) float lds_k[PXB * LSTR];
  __shared__ __align__(16) float lds_q[PXB * LSTR];

  const int t        = threadIdx.x;
  const int pixblock = blockIdx.x * PXB;
  // [b,c,h,w]: elem(b,c,phw) = (b<<20) + (c<<14) + phw; blocks never straddle b
  const int gbase = ((pixblock >> 14) << 20) | (pixblock & (HW - 1));

  const int lane = t & 63;
  const int p    = lane >> 3;                  // pixel-in-wave [0,8)
  const int ig   = lane & 7;                   // i-group [0,8): channels ig*8..+7
  const int px   = (t >> 6) * 8 + p;           // pixel-in-block [0,32)
  const int base  = gbase + px;
  const int cbase = base + (ig << 17);         // c = ig*8

  // my 8 v-channels (packed pairs), pre-scaled: x = v*log2e*k, e = 2^x
  float2 vv2[4];
#pragma unroll
  for (int n = 0; n < 4; ++n) {
    float a = v[cbase + ((2 * n) << 14)];
    float b = v[cbase + ((2 * n + 1) << 14)];
    vv2[n] = make_float2(a * LOG2E, b * LOG2E);
  }

  // ---- stage k,q: 64 j x 32 px, fully coalesced float4 loads along px ----
#pragma unroll
  for (int rep = 0; rep < 2; ++rep) {
    const int s  = rep * 256 + t;     // float4-slot [0,512)
    const int j  = s >> 3;            // [0,64)
    const int pg = (s & 7) * 4;       // px group start
    float4 k4 = *(const float4*)&kk[gbase + (j << 14) + pg];
    float4 q4 = *(const float4*)&q [gbase + (j << 14) + pg];
    lds_k[(pg + 0) * LSTR + j] = k4.x;  lds_q[(pg + 0) * LSTR + j] = q4.x;
    lds_k[(pg + 1) * LSTR + j] = k4.y;  lds_q[(pg + 1) * LSTR + j] = q4.y;
    lds_k[(pg + 2) * LSTR + j] = k4.z;  lds_q[(pg + 2) * LSTR + j] = q4.z;
    lds_k[(pg + 3) * LSTR + j] = k4.w;  lds_q[(pg + 3) * LSTR + j] = q4.w;
  }

  float2 acc2[4];
#pragma unroll
  for (int n = 0; n < 4; ++n) acc2[n] = make_float2(0.0f, 0.0f);

  __syncthreads();

  const float4* lkp4 = (const float4*)&lds_k[px * LSTR];
  const float4* lqp4 = (const float4*)&lds_q[px * LSTR];

  float4 kx4 = lkp4[0];
  float4 qx4 = lqp4[0];

#pragma unroll 1
  for (int jt = 0; jt < C / JT; ++jt) {
    const int nxt = (jt < C / JT - 1) ? jt + 1 : jt;
    float4 kxn = lkp4[nxt];               // prefetch next tile
    float4 qxn = lqp4[nxt];

    const float kx[JT] = {kx4.x, kx4.y, kx4.z, kx4.w};
    const float qx[JT] = {qx4.x, qx4.y, qx4.z, qx4.w};

    // 32 exps per tile: n=0,1 via trans pipe, n=2,3 via VALU bit-trick
    float2 e2[JT][4];
#pragma unroll
    for (int jj = 0; jj < JT; ++jj) {
#pragma unroll
      for (int n = 0; n < 2; ++n) {
        float mx = vv2[n].x * kx[jj];
        float my = vv2[n].y * kx[jj];
        e2[jj][n] = make_float2(__builtin_amdgcn_exp2f(mx),
                                __builtin_amdgcn_exp2f(my));
      }
#pragma unroll
      for (int n = 2; n < 4; ++n) {
        float mx = vv2[n].x * kx[jj];
        float my = vv2[n].y * kx[jj];
        e2[jj][n] = make_float2(exp2_valu(mx), exp2_valu(my));
      }
    }

    // batched column sums: packed tree + 3-stage DPP over the 8-lane group
    float S[JT];
#pragma unroll
    for (int jj = 0; jj < JT; ++jj) {
      float2 a = make_float2(e2[jj][0].x + e2[jj][1].x, e2[jj][0].y + e2[jj][1].y);
      float2 b = make_float2(e2[jj][2].x + e2[jj][3].x, e2[jj][2].y + e2[jj][3].y);
      float2 c = make_float2(a.x + b.x, a.y + b.y);
      S[jj] = c.x + c.y;
    }
#pragma unroll
    for (int jj = 0; jj < JT; ++jj) S[jj] = dpp_add<0xB1>(S[jj]);   // xor1
#pragma unroll
    for (int jj = 0; jj < JT; ++jj) S[jj] = dpp_add<0x4E>(S[jj]);   // xor2
#pragma unroll
    for (int jj = 0; jj < JT; ++jj) S[jj] = dpp_add<0x141>(S[jj]);  // i^7

#pragma unroll
    for (int jj = 0; jj < JT; ++jj) {
      const float w = qx[jj] * __builtin_amdgcn_rcpf(S[jj]);
#pragma unroll
      for (int n = 0; n < 4; ++n) {
        acc2[n].x += w * e2[jj][n].x;
        acc2[n].y += w * e2[jj][n].y;
      }
    }

    kx4 = kxn;
    qx4 = qxn;
  }

#pragma unroll
  for (int n = 0; n < 4; ++n) {
    out[cbase + ((2 * n) << 14)]     = acc2[n].x;
    out[cbase + ((2 * n + 1) << 14)] = acc2[n].y;
  }
}

extern "C" void kernel_launch(void* const* d_in, const int* in_sizes, int n_in,
                              void* d_out, int out_size, void* d_ws, size_t ws_size,
                              hipStream_t stream) {
  const float* q  = (const float*)d_in[0];  // x
  const float* kk = (const float*)d_in[1];  // y
  const float* v  = (const float*)d_in[2];  // z
  float* out = (float*)d_out;

  dim3 grid(NPIX / PXB);   // 1024 blocks x 256 threads, 32 px per block
  dim3 block(256);
  channel_mixing_kernel<<<grid, block, 0, stream>>>(q, kk, v, out);
}